// Round 23
// baseline (52.375 us; speedup 1.0000x reference)
//
#include <hip/hip_runtime.h>

#define N2 (768 * 768)
#define NH 32
#define PPB 256      // pairs per block == threads; 2304 blocks (all co-resident)
#define TPB 256

typedef float v4f __attribute__((ext_vector_type(4)));

// ---------- Pass 1: parallel block-boundary search ----------
// key(e) = (coeff==0 ? INT_MAX : pair[e]) is globally sorted (pair_idx sorted
// ascending over valid prefix, padding coeff==0 at the tail). bnd[j] =
// lower_bound(key, j*PPB). 2305 independent searches, fully parallel.
// Window [bnd[j], bnd[j+1]) therefore contains ONLY valid entries with
// pair in [j*PPB, (j+1)*PPB).
__global__ void bounds_kernel(const int* __restrict__ pair,
                              const float* __restrict__ coeff,
                              int* __restrict__ bnd, int M) {
    int j = blockIdx.x * blockDim.x + threadIdx.x;
    if (j > N2 / PPB) return;
    int target = j * PPB;
    int lo = 0, hi = M;
    while (lo < hi) {
        int mid = (lo + hi) >> 1;
        int key = (coeff[mid] == 0.f) ? 0x7fffffff : pair[mid];
        if (key < target) lo = mid + 1; else hi = mid;
    }
    bnd[j] = lo;
}

// ---------- Pass 2: one pair per thread, vectorized segment loads ----------
// out[h,p] = b[h]*S0[p] + sum_k W[h][k]*S[k][p], S0 = sum_e c_e,
// S[k] = sum_e c_e*ea[node_e][k] over pair p's contiguous entry segment.
// Thread t: lower_bound for pair p inside the block's L2-hot window (~12
// probes, early probes wave-broadcast); segment end = neighbor's start via
// LDS. Accumulate in 4-entry groups: one int4(node) + one float4(coeff) load
// (16B-aligned; M%4==0 keeps loads in-bounds) + 4 independent L1-hot ea
// gathers; entries outside [s,e) masked to c=0 (exact: they belong to
// neighbor pairs). ~5 independent iterations -> deep MLP, no LDS staging, no
// boundary pass. Expansion: 32 scalar stores, lane-consecutive p -> 256B
// contiguous per plane per wave (full lines). Every output element written
// exactly once; empty pairs (s==e) accumulate zero -> exact zeros.
__global__ __launch_bounds__(256) void fused_kernel(
    const int* __restrict__ pair, const int* __restrict__ node,
    const float* __restrict__ coeff, const float* __restrict__ ea,
    const float* __restrict__ W, const float* __restrict__ bias,
    const int* __restrict__ bnd, float* __restrict__ out)
{
    __shared__ int ss[TPB + 1];
    __shared__ float sW[NH * 4];
    __shared__ float sBias[NH];

    const int t = threadIdx.x;
    const int p0 = blockIdx.x * PPB;
    const int p = p0 + t;

    if (t < NH * 4) sW[t] = W[t];
    if (t < NH) sBias[t] = bias[t];

    const int s0 = bnd[blockIdx.x], s1 = bnd[blockIdx.x + 1];

    // lower_bound for p within [s0, s1) on pair[] (window is all-valid)
    {
        int lo = s0, hi = s1;
        while (lo < hi) {
            int mid = (lo + hi) >> 1;
            if (pair[mid] < p) lo = mid + 1; else hi = mid;
        }
        ss[t] = lo;
    }
    if (t == 0) ss[TPB] = s1;
    __syncthreads();

    const int s = ss[t], e = ss[t + 1];

    float a0 = 0.f, a1 = 0.f, a2 = 0.f, a3 = 0.f, a4 = 0.f;
    for (int g = (s & ~3) >> 2; (g << 2) < e; ++g) {
        const int4   n4 = reinterpret_cast<const int4*>(node)[g];
        const float4 c4 = reinterpret_cast<const float4*>(coeff)[g];
        const int ei = g << 2;
        // range mask (only first/last group can be partial)
        const float c0 = (ei     >= s && ei     < e) ? c4.x : 0.f;
        const float c1 = (ei + 1 >= s && ei + 1 < e) ? c4.y : 0.f;
        const float c2 = (ei + 2 >= s && ei + 2 < e) ? c4.z : 0.f;
        const float c3 = (ei + 3 >= s && ei + 3 < e) ? c4.w : 0.f;
        // 4 independent ea gathers (12 KB table, L1-hot)
        const float4 ex = *reinterpret_cast<const float4*>(ea + n4.x * 4);
        const float4 ey = *reinterpret_cast<const float4*>(ea + n4.y * 4);
        const float4 ez = *reinterpret_cast<const float4*>(ea + n4.z * 4);
        const float4 ew = *reinterpret_cast<const float4*>(ea + n4.w * 4);
        a0 += c0 + c1 + c2 + c3;
        a1 += c0 * ex.x + c1 * ey.x + c2 * ez.x + c3 * ew.x;
        a2 += c0 * ex.y + c1 * ey.y + c2 * ez.y + c3 * ew.y;
        a3 += c0 * ex.z + c1 * ey.z + c2 * ez.z + c3 * ew.z;
        a4 += c0 * ex.w + c1 * ey.w + c2 * ez.w + c3 * ew.w;
    }

    // expansion: 32 channels, lane-consecutive p -> 256B/plane/wave
#pragma unroll
    for (int h = 0; h < NH; ++h) {
        const float val = sBias[h] * a0 + sW[h * 4 + 0] * a1 + sW[h * 4 + 1] * a2
                        + sW[h * 4 + 2] * a3 + sW[h * 4 + 3] * a4;
        __builtin_nontemporal_store(val, out + (size_t)h * N2 + p);
    }
}

extern "C" void kernel_launch(void* const* d_in, const int* in_sizes, int n_in,
                              void* d_out, int out_size, void* d_ws, size_t ws_size,
                              hipStream_t stream) {
    // inputs: 0=x 1=edge_attr 2=W 3=b 4=edge_idx 5=pair_idx 6=node_idx 7=coeff 8=num_nodes
    const float* ea    = (const float*)d_in[1];
    const float* W     = (const float*)d_in[2];
    const float* b     = (const float*)d_in[3];
    const int*   pair  = (const int*)d_in[5];
    const int*   node  = (const int*)d_in[6];
    const float* coeff = (const float*)d_in[7];
    float* out = (float*)d_out;
    int M = in_sizes[5];

    int* bnd = (int*)d_ws;   // N2/PPB + 1 = 2305 ints

    bounds_kernel<<<(N2 / PPB + 1 + 255) / 256, 256, 0, stream>>>(pair, coeff, bnd, M);

    fused_kernel<<<N2 / PPB, TPB, 0, stream>>>(pair, node, coeff, ea, W, b, bnd, out);
}

// Round 24
// 50.824 us; speedup vs baseline: 1.0305x; 1.0305x over previous
//
#include <hip/hip_runtime.h>

#define N2 (768 * 768)
#define NH 32
#define NN 768       // nodes
#define PPB 64       // pairs per block; 9216 blocks
#define TPB 256      // 4 threads per pair, 4 waves
#define CAP 1280     // staged LDS entries; global-walk fallback beyond (~1% blocks)

typedef float v4f __attribute__((ext_vector_type(4)));

// ---------- Pass 1: parallel block-boundary search ----------
// key(e) = (coeff==0 ? INT_MAX : pair[e]) is globally sorted (pair_idx sorted
// ascending over valid prefix, padding coeff==0 at the tail). bnd[j] =
// lower_bound(key, j*PPB). 9217 independent searches, fully parallel.
__global__ void bounds_kernel(const int* __restrict__ pair,
                              const float* __restrict__ coeff,
                              int* __restrict__ bnd, int M) {
    int j = blockIdx.x * blockDim.x + threadIdx.x;
    if (j > N2 / PPB) return;
    int target = j * PPB;
    int lo = 0, hi = M;
    while (lo < hi) {
        int mid = (lo + hi) >> 1;
        int key = (coeff[mid] == 0.f) ? 0x7fffffff : pair[mid];
        if (key < target) lo = mid + 1; else hi = mid;
    }
    bnd[j] = lo;
}

// ---------- Pass 2: stage (+eaT) + walk + expand ----------
// out[h,p] = b[h]*S0[p] + sum_k W[h][k]*S[k][p] over pair p's entry segment.
// ea staged into LDS TRANSPOSED (eaT[k][n]): the walk's per-entry access is
// 4 independent ds_read_b32 at bank n%32 (64 random lanes over 32 banks ~
// 2/bank = conflict-free) -> replaces 10M divergent L1 TA gathers (the
// cross-round plateau) with throughput-bound LDS reads. Entry staging
// vectorized (int4/int4/float4 16B/lane; window 4-aligned; M%4==0 keeps
// loads in-bounds); run boundaries from registers. 4 thr/pair walk 2
// adjacent entries/iter (stride 8); 2-step shfl_xor merge; sums to LDS;
// expansion = 2 v4f NT stores/thread. Every output element written exactly
// once; missing pairs keep ps=pe=0 -> exact zeros, matching segment_sum.
__global__ __launch_bounds__(256) void fused_kernel(
    const int* __restrict__ pair, const int* __restrict__ node,
    const float* __restrict__ coeff, const float* __restrict__ ea,
    const float* __restrict__ W, const float* __restrict__ bias,
    const int* __restrict__ bnd, float* __restrict__ out, int M)
{
    __shared__ float eaT[4][NN];         // 12 KB transposed ea
    __shared__ float2 ent[CAP];          // 10 KB
    __shared__ float sum[5][PPB];        // 1.25 KB
    __shared__ int ps[PPB], pe[PPB];
    __shared__ float sW[NH * 4];
    __shared__ float sBias[NH];

    const int t = threadIdx.x;
    const int p0 = blockIdx.x * PPB;

    if (t < NH * 4) sW[t] = W[t];
    if (t < NH) sBias[t] = bias[t];
    if (t < PPB) { ps[t] = 0; pe[t] = 0; }
    // transpose-stage ea: lanes write consecutive n -> conflict-free
    for (int n = t; n < NN; n += TPB) {
        const float4 v = *reinterpret_cast<const float4*>(ea + n * 4);
        eaT[0][n] = v.x; eaT[1][n] = v.y; eaT[2][n] = v.z; eaT[3][n] = v.w;
    }
    __syncthreads();

    const int s0 = bnd[blockIdx.x], s1 = bnd[blockIdx.x + 1];
    const int s0a = s0 & ~3;             // 4-aligned staging base
    const int cntA = s1 - s0a;           // staged span
    const bool staged = (cntA <= CAP);   // block-uniform

    if (staged) {
        for (int i4 = t; (i4 << 2) < cntA; i4 += TPB) {
            const int e0 = s0a + (i4 << 2);
            const int4   p4 = reinterpret_cast<const int4*>(pair)[e0 >> 2];
            const int4   n4 = reinterpret_cast<const int4*>(node)[e0 >> 2];
            const float4 c4 = reinterpret_cast<const float4*>(coeff)[e0 >> 2];
            v4f w0; w0.x = c4.x; w0.y = __int_as_float(n4.x);
                    w0.z = c4.y; w0.w = __int_as_float(n4.y);
            v4f w1; w1.x = c4.z; w1.y = __int_as_float(n4.z);
                    w1.z = c4.w; w1.w = __int_as_float(n4.w);
            *reinterpret_cast<v4f*>(&ent[i4 << 2])       = w0;
            *reinterpret_cast<v4f*>(&ent[(i4 << 2) + 2]) = w1;
            const int prevp = (e0 > 0) ? pair[e0 - 1] : -1;
            const int nextp = (e0 + 4 < M) ? pair[e0 + 4] : -1;
            const int pk[6] = { prevp, p4.x, p4.y, p4.z, p4.w, nextp };
#pragma unroll
            for (int j = 0; j < 4; ++j) {
                const int e = e0 + j;
                const int pp = pk[j + 1];
                if (e >= s0 && e < s1) {
                    if (e == s0 || pk[j] != pp) ps[pp - p0] = e;
                    if (e == s1 - 1 || pk[j + 2] != pp) pe[pp - p0] = e + 1;
                }
            }
        }
    } else {
        const int cnt = s1 - s0;
        for (int i = t; i < cnt; i += TPB) {
            int e = s0 + i;
            int pp = pair[e];
            if (i == 0 || pair[e - 1] != pp) ps[pp - p0] = e;
            if (i == cnt - 1 || pair[e + 1] != pp) pe[pp - p0] = e + 1;
        }
    }
    __syncthreads();

    // 4 threads/pair, 2 adjacent entries per iteration (stride 8):
    // q = t>>2, sub = t&3 -> entries s+2sub, s+2sub+1, s+2sub+8, ...
    const int q = t >> 2, sub = t & 3;
    float a0 = 0.f, a1 = 0.f, a2 = 0.f, a3 = 0.f, a4 = 0.f;
    float b0s = 0.f, b1s = 0.f, b2s = 0.f, b3s = 0.f, b4s = 0.f;
    {
        const int e = pe[q];
        int k = ps[q] + (sub << 1);
        if (staged) {
            for (; k < e; k += 8) {
                const float2 enA = ent[k - s0a];
                const float ccA = enA.x;
                const int nA = __float_as_int(enA.y);
                a0 += ccA;
                a1 += ccA * eaT[0][nA]; a2 += ccA * eaT[1][nA];
                a3 += ccA * eaT[2][nA]; a4 += ccA * eaT[3][nA];
                if (k + 1 < e) {
                    const float2 enB = ent[k + 1 - s0a];
                    const float ccB = enB.x;
                    const int nB = __float_as_int(enB.y);
                    b0s += ccB;
                    b1s += ccB * eaT[0][nB]; b2s += ccB * eaT[1][nB];
                    b3s += ccB * eaT[2][nB]; b4s += ccB * eaT[3][nB];
                }
            }
        } else {
            for (; k < e; k += 8) {
                const float ccA = coeff[k];
                const int nA = node[k];
                a0 += ccA;
                a1 += ccA * eaT[0][nA]; a2 += ccA * eaT[1][nA];
                a3 += ccA * eaT[2][nA]; a4 += ccA * eaT[3][nA];
                if (k + 1 < e) {
                    const float ccB = coeff[k + 1];
                    const int nB = node[k + 1];
                    b0s += ccB;
                    b1s += ccB * eaT[0][nB]; b2s += ccB * eaT[1][nB];
                    b3s += ccB * eaT[2][nB]; b4s += ccB * eaT[3][nB];
                }
            }
        }
    }
    a0 += b0s; a1 += b1s; a2 += b2s; a3 += b3s; a4 += b4s;
#pragma unroll
    for (int d = 1; d < 4; d <<= 1) {
        a0 += __shfl_xor(a0, d); a1 += __shfl_xor(a1, d); a2 += __shfl_xor(a2, d);
        a3 += __shfl_xor(a3, d); a4 += __shfl_xor(a4, d);
    }
    if (sub == 0) {
        sum[0][q] = a0; sum[1][q] = a1; sum[2][q] = a2;
        sum[3][q] = a3; sum[4][q] = a4;
    }
    __syncthreads();

    // expansion: wave w, lane l; group g = l&15 -> pairs 4g..4g+3;
    // channels h = w*8 + (l>>4)*2 + j, j in {0,1}.
    {
        const int l = t & 63, w = t >> 6;
        const int g = l & 15, quad = l >> 4;
        const v4f c0 = *reinterpret_cast<const v4f*>(&sum[0][4 * g]);
        const v4f c1 = *reinterpret_cast<const v4f*>(&sum[1][4 * g]);
        const v4f c2 = *reinterpret_cast<const v4f*>(&sum[2][4 * g]);
        const v4f c3 = *reinterpret_cast<const v4f*>(&sum[3][4 * g]);
        const v4f c4 = *reinterpret_cast<const v4f*>(&sum[4][4 * g]);
        const size_t op = (size_t)p0 + 4 * g;
#pragma unroll
        for (int j = 0; j < 2; ++j) {
            const int h = w * 8 + quad * 2 + j;
            const float bb = sBias[h], w0 = sW[h * 4], w1 = sW[h * 4 + 1],
                        w2 = sW[h * 4 + 2], w3 = sW[h * 4 + 3];
            v4f o = bb * c0 + w0 * c1 + w1 * c2 + w2 * c3 + w3 * c4;
            __builtin_nontemporal_store(o, reinterpret_cast<v4f*>(out + (size_t)h * N2 + op));
        }
    }
}

extern "C" void kernel_launch(void* const* d_in, const int* in_sizes, int n_in,
                              void* d_out, int out_size, void* d_ws, size_t ws_size,
                              hipStream_t stream) {
    // inputs: 0=x 1=edge_attr 2=W 3=b 4=edge_idx 5=pair_idx 6=node_idx 7=coeff 8=num_nodes
    const float* ea    = (const float*)d_in[1];
    const float* W     = (const float*)d_in[2];
    const float* b     = (const float*)d_in[3];
    const int*   pair  = (const int*)d_in[5];
    const int*   node  = (const int*)d_in[6];
    const float* coeff = (const float*)d_in[7];
    float* out = (float*)d_out;
    int M = in_sizes[5];

    int* bnd = (int*)d_ws;   // N2/PPB + 1 = 9217 ints

    bounds_kernel<<<(N2 / PPB + 1 + 255) / 256, 256, 0, stream>>>(pair, coeff, bnd, M);

    fused_kernel<<<N2 / PPB, TPB, 0, stream>>>(pair, node, coeff, ea, W, b, bnd, out, M);
}